// Round 14
// baseline (1211.001 us; speedup 1.0000x reference)
//
#include <hip/hip_runtime.h>
#include <math.h>

#define NL 16
#define R1 513                       // (RMAX+1) allocated leading dim of input grids
#define LVL_STRIDE (R1 * R1 * 2)     // floats per level
#define HID 128
#define IN_DIM 32
#define NWAVES 8                     // 512-thread block: 8 waves share one weight copy

typedef float f32x4 __attribute__((ext_vector_type(4)));
typedef short s16x8 __attribute__((ext_vector_type(8)));   // 8 bf16 (4 VGPRs)

struct LvlArg { int r[NL]; int start[NL]; };   // start = cell offset of level l (4B cells)

static __device__ __forceinline__ unsigned short f2h(float f) {
    __bf16 b = (__bf16)f;                       // RNE f32->bf16
    return __builtin_bit_cast(unsigned short, b);
}
static __device__ __forceinline__ float ubl(unsigned u) {   // low bf16 -> f32
    return __builtin_bit_cast(float, u << 16);
}
static __device__ __forceinline__ float ubh(unsigned u) {   // high bf16 -> f32
    return __builtin_bit_cast(float, u & 0xffff0000u);
}

// ---------------------------------------------------------------------------
// Pass 1: bf16-compact pack. One 4B word per (level, ix, iy):
//   lo16 = bf16(f0), hi16 = bf16(f1). Compact (r+1)^2 rows (no R1=513 pad).
// Total = 2.85 MB -> fits EVERY XCD's 4MB L2 -> all gather fills become
// ~300cy L2 hits (R13 lesson: quad-pack's 11.4MB footprint blew L2; the
// fill LATENCY class, not the fill count, is the first-order term).
// ---------------------------------------------------------------------------
__global__ __launch_bounds__(256)
void build_pack(const float* __restrict__ grids, unsigned* __restrict__ q, LvlArg la)
{
    const int l = blockIdx.y;
    const int r = la.r[l];
    const int w = r + 1;
    const int cells = w * w;
    const float2* g = (const float2*)(grids + (size_t)l * LVL_STRIDE);
    unsigned* qb = q + la.start[l];
    for (int c = blockIdx.x * 256 + threadIdx.x; c < cells; c += gridDim.x * 256) {
        int ix = c / w, iy = c - ix * w;
        float2 f = g[ix * R1 + iy];               // coalesced along iy
        qb[c] = (unsigned)f2h(f.x) | ((unsigned)f2h(f.y) << 16);
    }
}

// ---------------------------------------------------------------------------
// Pass 2: fused encode + MLP. R5 shape: MT=1, 8 waves sharing one weight copy,
// (512,2) -> VGPR=128 + AGPRs, no spill (R3/R11: never force 4 waves/EU on
// this structure). Gather: 4 dword loads/level from the L2-resident pack.
// ---------------------------------------------------------------------------
__global__ __launch_bounds__(512, 2)
void ngp_mfma(const float* __restrict__ x,
              const unsigned* __restrict__ q,
              const float* __restrict__ W1, const float* __restrict__ b1,
              const float* __restrict__ W2, const float* __restrict__ b2,
              const float* __restrict__ W3, const float* __restrict__ b3,
              float* __restrict__ out, int n_pts, LvlArg la)
{
    // LDS: W1^T 8KB + W2^T 32KB + misc ~1.7KB + 8 per-wave h1 tiles 32KB = ~73.7KB
    __shared__ unsigned short w1t[IN_DIM * HID];      // [n=128][k=32] bf16, swizzled
    __shared__ unsigned short w2t[HID * HID];         // [n=128][k=128] bf16, swizzled
    __shared__ float b1s[HID], b2s[HID], w3s[HID];
    __shared__ int rs_s[NL], st_s[NL];
    __shared__ unsigned short h1t[NWAVES][16 * HID];  // per-wave transpose tile (swizzled)

    const int tid = threadIdx.x;

    // ---- setup: stage weights (transposed, bf16, XOR-swizzled) ----
    for (int idx = tid; idx < IN_DIM * HID; idx += 512) {
        int n = idx & 127, k = idx >> 7;              // W1 global is [k][n], read coalesced
        w1t[(n * IN_DIM + k) ^ ((n & 7) << 3)] = f2h(W1[idx]);
    }
    for (int idx = tid; idx < HID * HID; idx += 512) {
        int n = idx & 127, k = idx >> 7;              // W2 global is [k][n]
        w2t[(n * HID + k) ^ ((n & 7) << 3)] = f2h(W2[idx]);
    }
    if (tid < HID) { b1s[tid] = b1[tid]; b2s[tid] = b2[tid]; w3s[tid] = W3[tid]; }
    if (tid == 0) {
        #pragma unroll
        for (int l = 0; l < NL; ++l) { rs_s[l] = la.r[l]; st_s[l] = la.start[l]; }
    }
    __syncthreads();

    const int lane = tid & 63;
    const int wv   = tid >> 6;
    const int g    = lane >> 4;      // k-slice group (also level group 4g..4g+3)
    const int cl   = lane & 15;      // row/col lane id
    unsigned short* myh1 = h1t[wv];

    // per-lane level tables (levels 4g..4g+3), hoisted; dynamic index via LDS only
    int lr[4], lw[4]; float lrf[4]; const unsigned* qp[4];
    #pragma unroll
    for (int lv = 0; lv < 4; ++lv) {
        int L  = 4 * g + lv;
        int r  = rs_s[L];
        lr[lv] = r; lw[lv] = r + 1; lrf[lv] = (float)r;
        qp[lv] = q + st_s[L];
    }

    const int gw = blockIdx.x * NWAVES + wv;
    const int nw = gridDim.x * NWAVES;
    const float bias3 = b3[0];

    for (int base = gw * 16; base < n_pts; base += nw * 16) {

        // ---- gather: 4 dword loads per level (all L2-resident) -> A-fragment ----
        s16x8 fa;
        {
            int pt = min(base + cl, n_pts - 1);
            float2 xv = *(const float2*)(x + 2 * pt);
            #pragma unroll
            for (int lv = 0; lv < 4; ++lv) {
                int   r  = lr[lv], w = lw[lv];
                float px = xv.x * lrf[lv], py = xv.y * lrf[lv];
                float fx = floorf(px), fy = floorf(py);
                int ix0 = (int)fx; ix0 = max(0, min(ix0, r));
                int iy0 = (int)fy; iy0 = max(0, min(iy0, r));
                int iy1 = min(iy0 + 1, r);
                int row0 = ix0 * w;
                int row1 = min(ix0 + 1, r) * w;
                float wx = px - fx, wy = py - fy;
                float omx = 1.f - wx, omy = 1.f - wy;
                unsigned u00 = qp[lv][row0 + iy0];
                unsigned u01 = qp[lv][row0 + iy1];
                unsigned u10 = qp[lv][row1 + iy0];
                unsigned u11 = qp[lv][row1 + iy1];
                float vx = (ubl(u00) * omx + ubl(u10) * wx) * omy
                         + (ubl(u01) * omx + ubl(u11) * wx) * wy;
                float vy = (ubh(u00) * omx + ubh(u10) * wx) * omy
                         + (ubh(u01) * omx + ubh(u11) * wx) * wy;
                fa[2 * lv + 0] = (short)f2h(vx);      // k = 8g + 2*lv + f
                fa[2 * lv + 1] = (short)f2h(vy);
            }
        }

        // ---- layer 1: D[pt][neuron] = feats @ W1 + b1 (K=32, one MFMA step) ----
        f32x4 acc1[8];
        #pragma unroll
        for (int t = 0; t < 8; ++t) {
            int n = t * 16 + cl;
            float bb = b1s[n];
            s16x8 w1f = *(const s16x8*)&w1t[(n * IN_DIM + 8 * g) ^ ((n & 7) << 3)];
            f32x4 c = {bb, bb, bb, bb};
            acc1[t] = __builtin_amdgcn_mfma_f32_16x16x32_bf16(fa, w1f, c, 0, 0, 0);
        }

        // ---- relu -> bf16 -> per-wave LDS transpose -> layer-2 A-frags ----
        s16x8 ha[4];
        #pragma unroll
        for (int t = 0; t < 8; ++t) {
            int col = t * 16 + cl;
            f32x4 v = acc1[t];
            #pragma unroll
            for (int j = 0; j < 4; ++j) {
                int row = 4 * g + j;                  // D row = point-in-tile
                myh1[(row * HID + col) ^ ((row & 7) << 3)] = f2h(fmaxf(v[j], 0.f));
            }
        }
        #pragma unroll
        for (int s = 0; s < 4; ++s)                   // A-frag: row=cl, k=32s+8g..+7
            ha[s] = *(const s16x8*)&myh1[(cl * HID + s * 32 + 8 * g) ^ ((cl & 7) << 3)];

        // ---- layer 2: K=128 in 4 MFMA steps ----
        f32x4 acc2[8];
        #pragma unroll
        for (int t = 0; t < 8; ++t) {
            float bb = b2s[t * 16 + cl];
            f32x4 c = {bb, bb, bb, bb};
            acc2[t] = c;
        }
        #pragma unroll
        for (int s = 0; s < 4; ++s) {
            #pragma unroll
            for (int t = 0; t < 8; ++t) {
                int n = t * 16 + cl;
                s16x8 w2f = *(const s16x8*)&w2t[(n * HID + s * 32 + 8 * g) ^ ((n & 7) << 3)];
                acc2[t] = __builtin_amdgcn_mfma_f32_16x16x32_bf16(ha[s], w2f, acc2[t], 0, 0, 0);
            }
        }

        // ---- layer 3 (+ relu) fused epilogue: per-lane partials, 16-lane reduce ----
        {
            float o0 = 0.f, o1 = 0.f, o2 = 0.f, o3 = 0.f;
            #pragma unroll
            for (int t = 0; t < 8; ++t) {
                float w3v = w3s[t * 16 + cl];
                f32x4 v = acc2[t];
                o0 += fmaxf(v.x, 0.f) * w3v;
                o1 += fmaxf(v.y, 0.f) * w3v;
                o2 += fmaxf(v.z, 0.f) * w3v;
                o3 += fmaxf(v.w, 0.f) * w3v;
            }
            #pragma unroll
            for (int mask = 1; mask < 16; mask <<= 1) {
                o0 += __shfl_xor(o0, mask);
                o1 += __shfl_xor(o1, mask);
                o2 += __shfl_xor(o2, mask);
                o3 += __shfl_xor(o3, mask);
            }
            if (cl < 4) {
                int row = base + 4 * g + cl;
                float val = (cl == 0) ? o0 : (cl == 1) ? o1 : (cl == 2) ? o2 : o3;
                if (row < n_pts) out[row] = val + bias3;
            }
        }
    }
}

extern "C" void kernel_launch(void* const* d_in, const int* in_sizes, int n_in,
                              void* d_out, int out_size, void* d_ws, size_t ws_size,
                              hipStream_t stream)
{
    const float* x     = (const float*)d_in[0];
    const float* grids = (const float*)d_in[1];
    const float* W1    = (const float*)d_in[2];
    const float* b1    = (const float*)d_in[3];
    const float* W2    = (const float*)d_in[4];
    const float* b2    = (const float*)d_in[5];
    const float* W3    = (const float*)d_in[6];
    const float* b3    = (const float*)d_in[7];
    float* outp        = (float*)d_out;

    int n_pts = in_sizes[0] / 2;

    // RES = floor(16 * growth**l), growth = 32**(1/15); start = cumsum((r+1)^2)
    LvlArg la;
    double growth = pow(512.0 / 16.0, 1.0 / 15.0);
    int acc = 0;
    for (int l = 0; l < NL; ++l) {
        int r = (int)floor(16.0 * pow(growth, (double)l));
        la.r[l] = r;
        la.start[l] = acc;
        acc += (r + 1) * (r + 1);
    }
    // packed buffer = acc * 4B (~2.85 MB) at the front of d_ws, rebuilt every
    // launch (harness re-poisons d_ws before each timed call).
    unsigned* qbuf = (unsigned*)d_ws;

    build_pack<<<dim3(128, NL), 256, 0, stream>>>(grids, qbuf, la);

    dim3 block(512);
    dim3 grid(512);   // grid-stride; occupancy is register-capped at ~8 waves/CU (R11)
    hipLaunchKernelGGL(ngp_mfma, grid, block, 0, stream,
                       x, qbuf, W1, b1, W2, b2, W3, b3, outp, n_pts, la);
}